// Round 7
// baseline (101.119 us; speedup 1.0000x reference)
//
#include <hip/hip_runtime.h>
#include <math.h>

// Problem constants
#define BB 4
#define NN 8192
#define KK 16
#define DD 128
#define NPTS (BB * NN)          // 32768
#define GBLOCKS 2048            // gather: 8 blocks/CU -> 32 waves/CU
#define PAD 16                  // 64B line padding for atomic targets
#define BN_EPS 1e-5f

// ---------------------------------------------------------------------------
// Kernel 0: transpose proj_w -> wt[c][d] = w[d][c]; block 0 zeroes the
// padded BN accumulators (kernel-boundary ordering makes them visible).
// ---------------------------------------------------------------------------
__global__ void transpose_w(const float* __restrict__ w, float* __restrict__ wt,
                            float* gacc) {
    if (blockIdx.x == 0) {
        for (int j = threadIdx.x; j < 256 * PAD; j += 256) gacc[j] = 0.f;
    }
    int i = blockIdx.x * 256 + threadIdx.x;   // 16384 elements
    int d = i >> 7;
    int c = i & 127;
    wt[c * 128 + d] = w[d * 128 + c];
}

// ---------------------------------------------------------------------------
// Kernel 1: h[p][d] = sum_c x[p][c] * wt[c][d]
// 32-row tile / block -> 1024 blocks (4/CU, 16 waves/CU). Thread tile 4x4.
// ---------------------------------------------------------------------------
__global__ __launch_bounds__(256) void gemm_h(const float* __restrict__ x,
                                              const float* __restrict__ wt,
                                              float* __restrict__ h) {
    __shared__ float xs[32][128];
    const int block_row = blockIdx.x * 32;
    const int t = threadIdx.x;

    const float4* xg = reinterpret_cast<const float4*>(x + (size_t)block_row * 128);
    float4* xs4 = reinterpret_cast<float4*>(&xs[0][0]);
#pragma unroll
    for (int i = 0; i < 4; ++i) xs4[t + 256 * i] = xg[t + 256 * i];
    __syncthreads();

    const int ty = t >> 5;          // 0..7
    const int tx = t & 31;          // 0..31
    const int r0 = ty * 4;
    const int c0 = tx * 4;

    float acc[4][4];
#pragma unroll
    for (int r = 0; r < 4; ++r)
#pragma unroll
        for (int j = 0; j < 4; ++j) acc[r][j] = 0.f;

#pragma unroll 2
    for (int c4 = 0; c4 < 32; ++c4) {
        float4 wv[4];
#pragma unroll
        for (int j = 0; j < 4; ++j)
            wv[j] = *reinterpret_cast<const float4*>(wt + (size_t)(c4 * 4 + j) * 128 + c0);
#pragma unroll
        for (int r = 0; r < 4; ++r) {
            float4 xv = *reinterpret_cast<const float4*>(&xs[r0 + r][c4 * 4]);
            const float xc[4] = {xv.x, xv.y, xv.z, xv.w};
#pragma unroll
            for (int j = 0; j < 4; ++j) {
                acc[r][0] = fmaf(xc[j], wv[j].x, acc[r][0]);
                acc[r][1] = fmaf(xc[j], wv[j].y, acc[r][1]);
                acc[r][2] = fmaf(xc[j], wv[j].z, acc[r][2]);
                acc[r][3] = fmaf(xc[j], wv[j].w, acc[r][3]);
            }
        }
    }

#pragma unroll
    for (int r = 0; r < 4; ++r) {
        float4 o = make_float4(acc[r][0], acc[r][1], acc[r][2], acc[r][3]);
        *reinterpret_cast<float4*>(h + (size_t)(block_row + r0 + r) * 128 + c0) = o;
    }
}

// ---------------------------------------------------------------------------
// Kernel 2: gather + encode + max over K. Writes agg to out; publishes BN
// partials via padded atomicAdd (kernel boundary = sync; no grid barrier).
// Block: 256 thr = 8 point-slots x 32 groups; 2 its -> 16 points/block.
// Neighbor xyz handled cooperatively: lane k (g<16) computes rel once,
// broadcasts via LDS; k-loop per lane is 1 h-float4 + 1 ds_read_b128.
// __launch_bounds__(256,8): VGPR<=64 -> 8 blocks/CU, 32 waves/CU.
// ---------------------------------------------------------------------------
__global__ __launch_bounds__(256, 8) void gather_max(const float* __restrict__ h,
                                                     const float* __restrict__ xyz,
                                                     const int* __restrict__ knn,
                                                     const float* __restrict__ coor,
                                                     const float* __restrict__ scale,
                                                     float* __restrict__ out,
                                                     float* gacc) {
    const int t = threadIdx.x;
    const int g = t & 31;    // group id (channels 4g..4g+3)
    const int sub = t >> 5;  // point slot 0..7 (wave w owns subs 2w, 2w+1)

    // XCD batch-affinity swizzle: blk&7 ~ XCD; two XCDs share one batch.
    const int xcd = blockIdx.x & 7;
    const int jj = blockIdx.x >> 3;                 // 0..255
    const int slot = ((xcd & 1) << 8) + jj;         // 0..511 within batch
    const int b = xcd >> 1;                         // batch 0..3
    const int pbase = (b << 13) + (slot << 4);      // 16 points per block
    const int rowbase = b << 13;

    const float c0w = coor[g * 3 + 0];
    const float c1w = coor[g * 3 + 1];
    const float c2w = coor[g * 3 + 2];
    const float sg = scale[g];
    const float s2 = sg * sg;

    // relk[sub][k] = (rx, ry, rz, r2); each wave touches only its own subs.
    __shared__ float4 relk[8][16];   // 2 KB

    float lsum[4] = {0.f, 0.f, 0.f, 0.f};
    float lsq[4]  = {0.f, 0.f, 0.f, 0.f};

#pragma unroll
    for (int it = 0; it < 2; ++it) {
        const int p = pbase + it * 8 + sub;
        const float* ctr = xyz + (size_t)p * 3;
        const float cx = ctr[0], cy = ctr[1], cz = ctr[2];

        const int4* kn4 = reinterpret_cast<const int4*>(knn + (size_t)p * KK);
        const int4 ka = kn4[0], kb = kn4[1], kc = kn4[2], kd = kn4[3];
        int rows[16];
        rows[0] = rowbase + ka.x;  rows[1] = rowbase + ka.y;
        rows[2] = rowbase + ka.z;  rows[3] = rowbase + ka.w;
        rows[4] = rowbase + kb.x;  rows[5] = rowbase + kb.y;
        rows[6] = rowbase + kb.z;  rows[7] = rowbase + kb.w;
        rows[8] = rowbase + kc.x;  rows[9] = rowbase + kc.y;
        rows[10] = rowbase + kc.z; rows[11] = rowbase + kc.w;
        rows[12] = rowbase + kd.x; rows[13] = rowbase + kd.y;
        rows[14] = rowbase + kd.z; rows[15] = rowbase + kd.w;

        // cooperative rel computation: lane g<16 handles neighbor k=g.
        if (g < 16) {
            const float* nb = xyz + (size_t)rows[g] * 3;
            const float rx = nb[0] - cx;
            const float ry = nb[1] - cy;
            const float rz = nb[2] - cz;
            relk[sub][g] = make_float4(rx, ry, rz, rx * rx + ry * ry + rz * rz);
        }
        // wave-internal LDS write->read ordering (no cross-wave dependency):
        asm volatile("s_waitcnt lgkmcnt(0)" ::: "memory");

        float4 acc = make_float4(-INFINITY, -INFINITY, -INFINITY, -INFINITY);

#pragma unroll
        for (int q = 0; q < 4; ++q) {
            float4 hv[4];
#pragma unroll
            for (int k = 0; k < 4; ++k)
                hv[k] = *reinterpret_cast<const float4*>(
                            h + (size_t)rows[q * 4 + k] * 128 + g * 4);
#pragma unroll
            for (int k = 0; k < 4; ++k) {
                const float4 r = relk[sub][q * 4 + k];
                const float e = fmaf(r.x, c0w, fmaf(r.y, c1w,
                                 fmaf(r.z, c2w, r.w * s2)));
                acc.x = fmaxf(acc.x, hv[k].x + e);
                acc.y = fmaxf(acc.y, hv[k].y + e);
                acc.z = fmaxf(acc.z, hv[k].z + e);
                acc.w = fmaxf(acc.w, hv[k].w + e);
            }
        }

        *reinterpret_cast<float4*>(out + (size_t)p * 128 + g * 4) = acc;

        lsum[0] += acc.x; lsum[1] += acc.y; lsum[2] += acc.z; lsum[3] += acc.w;
        lsq[0] += acc.x * acc.x; lsq[1] += acc.y * acc.y;
        lsq[2] += acc.z * acc.z; lsq[3] += acc.w * acc.w;
    }

    // block reduction across the 8 point-slots, publish via atomicAdd
    __shared__ float red[8][128];
#pragma unroll
    for (int j = 0; j < 4; ++j) red[sub][g * 4 + j] = lsum[j];
    __syncthreads();
    if (t < 128) {
        float s = 0.f;
#pragma unroll
        for (int s8 = 0; s8 < 8; ++s8) s += red[s8][t];
        __hip_atomic_fetch_add(&gacc[t * PAD], s,
                               __ATOMIC_RELAXED, __HIP_MEMORY_SCOPE_AGENT);
    }
    __syncthreads();
#pragma unroll
    for (int j = 0; j < 4; ++j) red[sub][g * 4 + j] = lsq[j];
    __syncthreads();
    if (t < 128) {
        float q = 0.f;
#pragma unroll
        for (int s8 = 0; s8 < 8; ++s8) q += red[s8][t];
        __hip_atomic_fetch_add(&gacc[(128 + t) * PAD], q,
                               __ATOMIC_RELAXED, __HIP_MEMORY_SCOPE_AGENT);
    }
}

// ---------------------------------------------------------------------------
// Kernel 3: in-place BN. Every block computes A/C from the 256 global
// accumulators (cheap, L2-broadcast), then grid-strides the normalize.
// ---------------------------------------------------------------------------
__global__ __launch_bounds__(256) void bn_apply(float* __restrict__ out,
                                                const float* __restrict__ gacc,
                                                const float* __restrict__ bnw,
                                                const float* __restrict__ bnb) {
    __shared__ __align__(16) float sA[128], sC[128];
    const int t = threadIdx.x;
    if (t < 128) {
        const float stot = gacc[t * PAD];
        const float qtot = gacc[(128 + t) * PAD];
        const float inv_n = 1.0f / (float)NPTS;
        const float mean = stot * inv_n;
        const float var = qtot * inv_n - mean * mean;
        const float rstd = rsqrtf(var + BN_EPS);
        const float A = rstd * bnw[t];
        sA[t] = A;
        sC[t] = bnb[t] - mean * A;
    }
    __syncthreads();

    const int stride = gridDim.x * 256;
    float4* out4 = reinterpret_cast<float4*>(out);
    const float4* A4 = reinterpret_cast<const float4*>(sA);
    const float4* C4 = reinterpret_cast<const float4*>(sC);
    for (int i = blockIdx.x * 256 + t; i < NPTS * DD / 4; i += stride) {
        const int ch4 = i & 31;
        float4 v = out4[i];
        const float4 A = A4[ch4];
        const float4 C = C4[ch4];
        v.x = fmaf(v.x, A.x, C.x);
        v.y = fmaf(v.y, A.y, C.y);
        v.z = fmaf(v.z, A.z, C.z);
        v.w = fmaf(v.w, A.w, C.w);
        out4[i] = v;
    }
}

// ---------------------------------------------------------------------------
extern "C" void kernel_launch(void* const* d_in, const int* in_sizes, int n_in,
                              void* d_out, int out_size, void* d_ws, size_t ws_size,
                              hipStream_t stream) {
    const float* x      = (const float*)d_in[0];
    const float* xyz    = (const float*)d_in[1];
    const int*   knn    = (const int*)d_in[2];
    const float* proj_w = (const float*)d_in[3];
    const float* coor   = (const float*)d_in[4];
    const float* scale  = (const float*)d_in[5];
    const float* bnw    = (const float*)d_in[6];
    const float* bnb    = (const float*)d_in[7];
    float* out = (float*)d_out;

    char* ws = (char*)d_ws;
    size_t off = 0;
    float* h    = (float*)(ws + off); off += (size_t)NPTS * DD * 4;   // 16 MB
    float* wt   = (float*)(ws + off); off += 65536;                   // 64 KB
    float* gacc = (float*)(ws + off); off += 256 * PAD * 4;           // padded sums

    transpose_w<<<64, 256, 0, stream>>>(proj_w, wt, gacc);
    gemm_h<<<NPTS / 32, 256, 0, stream>>>(x, wt, h);
    gather_max<<<GBLOCKS, 256, 0, stream>>>(h, xyz, knn, coor, scale, out, gacc);
    bn_apply<<<2048, 256, 0, stream>>>(out, gacc, bnw, bnb);
}